// Round 6
// baseline (943.702 us; speedup 1.0000x reference)
//
#include <hip/hip_runtime.h>

// Conditional-DETR decoder layer, MI355X gfx950. Round 6.
// Dtype model (pinned by rounds 1-5): inputs fp32, OUTPUT fp32 (comparison is
// done at bf16 precision — the "(bf16)" label — but the buffer is fp32).
// Evidence: round-4 (MFMA) and round-5 (VALU) builds gave bit-identical error
// 6.796875 -> both computed the same correct tensor; the error was the bf16
// output writes being read back as fp32 (odd-halfword scramble). MFMA layouts
// are validated. This round = round 4 + fp32 output writes only.
// D=768 H=6 HD=128 DFF=2048 L=512 S=1024 B=8, SCALE=1/16.

typedef __bf16 bf16;
typedef __attribute__((ext_vector_type(8))) __bf16 bf16x8;
typedef __attribute__((ext_vector_type(4))) float f32x4;

#define D_MODEL 768
#define NH 6
#define HD 128
#define ROWSTRIDE (8 * D_MODEL)  // 6144 (B*D)

// 8-element loaders -> bf16x8 (fp32 source converts in flight; 2x16B loads)
__device__ inline bf16x8 ld8(const bf16* p) { return *(const bf16x8*)p; }
__device__ inline bf16x8 ld8(const float* p) {
    f32x4 a = *(const f32x4*)p, b = *(const f32x4*)(p + 4);
    bf16x8 r;
#pragma unroll
    for (int i = 0; i < 4; i++) { r[i] = (bf16)a[i]; r[i + 4] = (bf16)b[i]; }
    return r;
}

// ---------------------------------------------------------------------------
// GEMM: C[M,N] = (A [+ A2])[M,K] * W[N,K]^T + bias, fp32 accum, bf16 out.
// A dtype templated; W/bias/A2 fp32 (harness inputs). Grid (N/128, M/128),
// block 256 = 4 waves (2x2), wave = 64x64 via 4x4 MFMAs.
// Layouts (learn_hip m89/m91, validated by round-4/5 A-B test):
// A-frag A[m=lane&15][k=quad*8+j], B-frag B[k=quad*8+j][n=lane&15],
// C/D row=quad*4+r col=lane&15.
template <typename TA, bool DUAL>
__global__ __launch_bounds__(256) void gemm_bt(
    const TA* __restrict__ A, const float* __restrict__ A2, int lda,
    const float* __restrict__ W, int ldw,
    const float* __restrict__ bias,
    bf16* __restrict__ C, int ldc, int K, int relu)
{
    __shared__ __align__(16) bf16 As[128][40];  // pad 32->40: 2-way alias only (free, m136)
    __shared__ __align__(16) bf16 Bs[128][40];
    const int bm = blockIdx.y * 128, bn = blockIdx.x * 128;
    const int tid = threadIdx.x;
    const int wave = tid >> 6, lane = tid & 63;
    const int wm = (wave >> 1) * 64, wn = (wave & 1) * 64;
    const int quad = lane >> 4, m16 = lane & 15;
    const int srow = tid >> 2, scol = (tid & 3) * 8;
    f32x4 acc[4][4] = {};
    const size_t aoff0 = (size_t)(bm + srow) * lda + scol;
    const size_t aoff1 = aoff0 + (size_t)64 * lda;
    const size_t woff0 = (size_t)(bn + srow) * ldw + scol;
    const size_t woff1 = woff0 + (size_t)64 * ldw;
    for (int k0 = 0; k0 < K; k0 += 32) {
        bf16x8 a0 = ld8(A + aoff0 + k0);
        bf16x8 a1 = ld8(A + aoff1 + k0);
        if (DUAL) {
            f32x4 e0a = *(const f32x4*)(A2 + aoff0 + k0), e0b = *(const f32x4*)(A2 + aoff0 + k0 + 4);
            f32x4 e1a = *(const f32x4*)(A2 + aoff1 + k0), e1b = *(const f32x4*)(A2 + aoff1 + k0 + 4);
#pragma unroll
            for (int i = 0; i < 4; i++) {
                a0[i]     = (bf16)((float)a0[i]     + e0a[i]);
                a0[i + 4] = (bf16)((float)a0[i + 4] + e0b[i]);
                a1[i]     = (bf16)((float)a1[i]     + e1a[i]);
                a1[i + 4] = (bf16)((float)a1[i + 4] + e1b[i]);
            }
        }
        *(bf16x8*)&As[srow][scol]      = a0;
        *(bf16x8*)&As[srow + 64][scol] = a1;
        *(bf16x8*)&Bs[srow][scol]      = ld8(W + woff0 + k0);
        *(bf16x8*)&Bs[srow + 64][scol] = ld8(W + woff1 + k0);
        __syncthreads();
        bf16x8 af[4], bfr[4];
#pragma unroll
        for (int i = 0; i < 4; i++) {
            af[i]  = *(const bf16x8*)&As[wm + i * 16 + m16][quad * 8];
            bfr[i] = *(const bf16x8*)&Bs[wn + i * 16 + m16][quad * 8];
        }
#pragma unroll
        for (int i = 0; i < 4; i++)
#pragma unroll
            for (int j = 0; j < 4; j++)
                acc[i][j] = __builtin_amdgcn_mfma_f32_16x16x32_bf16(af[i], bfr[j], acc[i][j], 0, 0, 0);
        __syncthreads();
    }
#pragma unroll
    for (int j = 0; j < 4; j++) {
        const int col = bn + wn + j * 16 + m16;
        const float bv = bias[col];
#pragma unroll
        for (int i = 0; i < 4; i++) {
#pragma unroll
            for (int r = 0; r < 4; r++) {
                const int row = bm + wm + i * 16 + quad * 4 + r;
                float val = acc[i][j][r] + bv;
                if (relu) val = fmaxf(val, 0.f);
                C[(size_t)row * ldc + col] = (bf16)val;
            }
        }
    }
}

// ---------------------------------------------------------------------------
// scores[bh, l, s] = SCALE * (qc_h . kc_h + qp_h . kp_h), K=256 (two 128 halves),
// bf16 out (|logit| small). Grid (S/128, Lq/128, B*H).
__global__ __launch_bounds__(256) void attn_scores(
    const bf16* __restrict__ qc, const bf16* __restrict__ qp,
    const bf16* __restrict__ kc, const bf16* __restrict__ kp,
    bf16* __restrict__ scores, int Lq, int S, float scale)
{
    __shared__ __align__(16) bf16 As[128][40];
    __shared__ __align__(16) bf16 Bs[128][40];
    const int bh = blockIdx.z;
    const int b = bh / NH, h = bh % NH;
    const int bm = blockIdx.y * 128, bn = blockIdx.x * 128;
    const int tid = threadIdx.x;
    const int wave = tid >> 6, lane = tid & 63;
    const int wm = (wave >> 1) * 64, wn = (wave & 1) * 64;
    const int quad = lane >> 4, m16 = lane & 15;
    const int srow = tid >> 2, scol = (tid & 3) * 8;
    f32x4 acc[4][4] = {};
    const size_t hb = (size_t)b * D_MODEL + h * HD;
    for (int k0 = 0; k0 < 256; k0 += 32) {
        const bf16* qsrc = (k0 < 128) ? qc : qp;
        const bf16* ksrc = (k0 < 128) ? kc : kp;
        const int kcol = (k0 & 127) + scol;
        *(bf16x8*)&As[srow][scol]      = *(const bf16x8*)(qsrc + (size_t)(bm + srow) * ROWSTRIDE + hb + kcol);
        *(bf16x8*)&As[srow + 64][scol] = *(const bf16x8*)(qsrc + (size_t)(bm + srow + 64) * ROWSTRIDE + hb + kcol);
        *(bf16x8*)&Bs[srow][scol]      = *(const bf16x8*)(ksrc + (size_t)(bn + srow) * ROWSTRIDE + hb + kcol);
        *(bf16x8*)&Bs[srow + 64][scol] = *(const bf16x8*)(ksrc + (size_t)(bn + srow + 64) * ROWSTRIDE + hb + kcol);
        __syncthreads();
        bf16x8 af[4], bfr[4];
#pragma unroll
        for (int i = 0; i < 4; i++) {
            af[i]  = *(const bf16x8*)&As[wm + i * 16 + m16][quad * 8];
            bfr[i] = *(const bf16x8*)&Bs[wn + i * 16 + m16][quad * 8];
        }
#pragma unroll
        for (int i = 0; i < 4; i++)
#pragma unroll
            for (int j = 0; j < 4; j++)
                acc[i][j] = __builtin_amdgcn_mfma_f32_16x16x32_bf16(af[i], bfr[j], acc[i][j], 0, 0, 0);
        __syncthreads();
    }
    bf16* srow_base = scores + (size_t)bh * Lq * S;
#pragma unroll
    for (int i = 0; i < 4; i++)
#pragma unroll
        for (int j = 0; j < 4; j++)
#pragma unroll
            for (int r = 0; r < 4; r++) {
                const int row = bm + wm + i * 16 + quad * 4 + r;
                const int col = bn + wn + j * 16 + m16;
                srow_base[(size_t)row * S + col] = (bf16)(acc[i][j][r] * scale);
            }
}

// ---------------------------------------------------------------------------
// Row softmax over bf16 rows in place; fp32 math. One block per row.
__global__ __launch_bounds__(256) void softmax_rows(bf16* __restrict__ scores, int S)
{
    bf16* p = scores + (size_t)blockIdx.x * S;
    const int tid = threadIdx.x;
    const int n = S >> 8;  // 2 or 4
    float vals[4];
    float mx = -1e30f;
    for (int i = 0; i < n; i++) { vals[i] = (float)p[tid + (i << 8)]; mx = fmaxf(mx, vals[i]); }
    for (int off = 32; off; off >>= 1) mx = fmaxf(mx, __shfl_xor(mx, off, 64));
    __shared__ float red[4], red2[4];
    if ((tid & 63) == 0) red[tid >> 6] = mx;
    __syncthreads();
    mx = fmaxf(fmaxf(red[0], red[1]), fmaxf(red[2], red[3]));
    float sum = 0.f;
    for (int i = 0; i < n; i++) { vals[i] = __expf(vals[i] - mx); sum += vals[i]; }
    for (int off = 32; off; off >>= 1) sum += __shfl_xor(sum, off, 64);
    if ((tid & 63) == 0) red2[tid >> 6] = sum;
    __syncthreads();
    const float inv = 1.f / (red2[0] + red2[1] + red2[2] + red2[3]);
    for (int i = 0; i < n; i++) p[tid + (i << 8)] = (bf16)(vals[i] * inv);
}

// att[b,l,s] = (1/H) sum_h w[((b*H+h)*Lq + l)*S + s] — fp32 OUTPUT
__global__ __launch_bounds__(256) void head_mean(
    const bf16* __restrict__ w, float* __restrict__ att, int Lq, int S)
{
    const size_t idx = (size_t)blockIdx.x * 256 + threadIdx.x;
    const size_t s = idx % S, rem = idx / S;
    const size_t l = rem % Lq, b = rem / Lq;
    float sum = 0.f;
#pragma unroll
    for (int h = 0; h < NH; h++)
        sum += (float)w[((b * NH + h) * Lq + l) * (size_t)S + s];
    att[idx] = sum * (1.f / 6.f);
}

// ---------------------------------------------------------------------------
// o[l, b, h*HD+e] = sum_s w[bh,l,s] * v[s,b,h*HD+e].  Grid (Lq/128, 1, B*H).
// V is K-strided: LDS transpose on staging, then b128 frag reads.
__global__ __launch_bounds__(256) void attn_pv(
    const bf16* __restrict__ wsm,
    const bf16* __restrict__ v,
    bf16* __restrict__ o, int Lq, int S)
{
    __shared__ __align__(16) bf16 As[128][40];
    __shared__ __align__(16) bf16 BsT[128][40];
    const int bh = blockIdx.z;
    const int b = bh / NH, h = bh % NH;
    const int bm = blockIdx.x * 128;
    const int tid = threadIdx.x;
    const int wave = tid >> 6, lane = tid & 63;
    const int wm = (wave >> 1) * 64, wn = (wave & 1) * 64;
    const int quad = lane >> 4, m16 = lane & 15;
    const int srow = tid >> 2, scol = (tid & 3) * 8;
    const int kk0 = tid >> 4, e0 = (tid & 15) * 8;
    f32x4 acc[4][4] = {};
    const bf16* wbase = wsm + (size_t)(bh * Lq + bm) * S;
    const size_t vb = (size_t)b * D_MODEL + h * HD;
    for (int k0 = 0; k0 < S; k0 += 32) {
        *(bf16x8*)&As[srow][scol]      = *(const bf16x8*)(wbase + (size_t)srow * S + k0 + scol);
        *(bf16x8*)&As[srow + 64][scol] = *(const bf16x8*)(wbase + (size_t)(srow + 64) * S + k0 + scol);
        bf16x8 v0 = *(const bf16x8*)(v + (size_t)(k0 + kk0) * ROWSTRIDE + vb + e0);
        bf16x8 v1 = *(const bf16x8*)(v + (size_t)(k0 + kk0 + 16) * ROWSTRIDE + vb + e0);
#pragma unroll
        for (int i = 0; i < 8; i++) { BsT[e0 + i][kk0] = v0[i]; BsT[e0 + i][kk0 + 16] = v1[i]; }
        __syncthreads();
        bf16x8 af[4], bfr[4];
#pragma unroll
        for (int i = 0; i < 4; i++) {
            af[i]  = *(const bf16x8*)&As[wm + i * 16 + m16][quad * 8];
            bfr[i] = *(const bf16x8*)&BsT[wn + i * 16 + m16][quad * 8];
        }
#pragma unroll
        for (int i = 0; i < 4; i++)
#pragma unroll
            for (int j = 0; j < 4; j++)
                acc[i][j] = __builtin_amdgcn_mfma_f32_16x16x32_bf16(af[i], bfr[j], acc[i][j], 0, 0, 0);
        __syncthreads();
    }
#pragma unroll
    for (int i = 0; i < 4; i++)
#pragma unroll
        for (int j = 0; j < 4; j++)
#pragma unroll
            for (int r = 0; r < 4; r++) {
                const int row = bm + wm + i * 16 + quad * 4 + r;  // l
                const int col = wn + j * 16 + m16;                // e in [0,128)
                o[(size_t)row * ROWSTRIDE + vb + col] = (bf16)acc[i][j][r];
            }
}

// ---------------------------------------------------------------------------
// out = LN(resid + x) * g + beta; resid/output dtypes templated, x bf16.
template <typename TR, typename TO>
__global__ __launch_bounds__(256) void add_ln(
    const TR* __restrict__ resid, const bf16* __restrict__ x,
    const float* __restrict__ g, const float* __restrict__ be,
    TO* __restrict__ out)
{
    const size_t base = (size_t)blockIdx.x * D_MODEL;
    const int tid = threadIdx.x;
    float v[3];
#pragma unroll
    for (int i = 0; i < 3; i++) {
        const int c = tid + (i << 8);
        v[i] = (float)resid[base + c] + (float)x[base + c];
    }
    float s = v[0] + v[1] + v[2];
    float s2 = v[0] * v[0] + v[1] * v[1] + v[2] * v[2];
    for (int off = 32; off; off >>= 1) { s += __shfl_xor(s, off, 64); s2 += __shfl_xor(s2, off, 64); }
    __shared__ float rs[4], rs2[4];
    if ((tid & 63) == 0) { rs[tid >> 6] = s; rs2[tid >> 6] = s2; }
    __syncthreads();
    s = rs[0] + rs[1] + rs[2] + rs[3];
    s2 = rs2[0] + rs2[1] + rs2[2] + rs2[3];
    const float mean = s * (1.f / 768.f);
    const float var = s2 * (1.f / 768.f) - mean * mean;
    const float inv = rsqrtf(var + 1e-5f);
#pragma unroll
    for (int i = 0; i < 3; i++) {
        const int c = tid + (i << 8);
        out[base + c] = (TO)((v[i] - mean) * inv * g[c] + be[c]);
    }
}

// ---------------------------------------------------------------------------
extern "C" void kernel_launch(void* const* d_in, const int* in_sizes, int n_in,
                              void* d_out, int out_size, void* d_ws, size_t ws_size,
                              hipStream_t stream)
{
    const float* tgt        = (const float*)d_in[0];
    const float* memory     = (const float*)d_in[1];
    const float* tgt_pos    = (const float*)d_in[2];
    const float* memory_pos = (const float*)d_in[3];
    const float* tgt_pos2   = (const float*)d_in[4];
    const float *sa_w[6], *sa_b[6], *ca_w[6], *ca_b[6];
    for (int i = 0; i < 6; i++) {
        sa_w[i] = (const float*)d_in[5 + 2 * i];  sa_b[i] = (const float*)d_in[6 + 2 * i];
        ca_w[i] = (const float*)d_in[17 + 2 * i]; ca_b[i] = (const float*)d_in[18 + 2 * i];
    }
    const float* ff1_w = (const float*)d_in[29]; const float* ff1_b = (const float*)d_in[30];
    const float* ff2_w = (const float*)d_in[31]; const float* ff2_b = (const float*)d_in[32];
    const float* ln_g[3] = {(const float*)d_in[33], (const float*)d_in[35], (const float*)d_in[37]};
    const float* ln_b[3] = {(const float*)d_in[34], (const float*)d_in[36], (const float*)d_in[38]};

    // ---- workspace: 106,954,752 bytes (identical to round 4) ----
    char* ws = (char*)d_ws;
    bf16* qc  = (bf16*)(ws);                // 6,291,456 B  (L*B*D bf16)
    bf16* qp  = (bf16*)(ws + 6291456);      // 6,291,456
    bf16* kc  = (bf16*)(ws + 12582912);     // 12,582,912   (S*B*D)
    bf16* kp  = (bf16*)(ws + 25165824);     // 12,582,912
    bf16* vv  = (bf16*)(ws + 37748736);     // 12,582,912
    bf16* t1  = (bf16*)(ws + 50331648);     // 6,291,456
    bf16* sc  = (bf16*)(ws + 56623104);     // 50,331,648   (B*H*L*S bf16, CA; SA prefix)
    bf16* ob  = qc;   // attn out: qc dead after scores
    bf16* t2  = qp;   // out-proj: qp dead after scores
    bf16* tca = kc;   // ln2 out:  kc dead after CA scores
    bf16* ffh = kp;   // FFN hidden 16.78 MB over dead kp+vv

    // ---- outputs: FP32, concatenated (t, att, self_att) ----
    float* out_t    = (float*)d_out;        // (L,B,D)    3,145,728 floats
    float* out_att  = out_t + 3145728;      // (B,L,S)    4,194,304
    float* out_satt = out_att + 4194304;    // (B,L,L)    2,097,152

    const dim3 blk(256);
    const float SCALE = 0.0625f;  // 1/sqrt(2*D/H) = 1/16

    // ---- self attention ----
    gemm_bt<float, false><<<dim3(6, 32), blk, 0, stream>>>(tgt_pos, nullptr, 768, sa_w[0], 768, sa_b[0], qc, 768, 768, 0);
    gemm_bt<float, false><<<dim3(6, 32), blk, 0, stream>>>(tgt,     nullptr, 768, sa_w[1], 768, sa_b[1], qp, 768, 768, 0);
    gemm_bt<float, false><<<dim3(6, 32), blk, 0, stream>>>(tgt_pos, nullptr, 768, sa_w[2], 768, sa_b[2], kc, 768, 768, 0);
    gemm_bt<float, false><<<dim3(6, 32), blk, 0, stream>>>(tgt,     nullptr, 768, sa_w[3], 768, sa_b[3], kp, 768, 768, 0);
    gemm_bt<float, false><<<dim3(6, 32), blk, 0, stream>>>(tgt,     nullptr, 768, sa_w[4], 768, sa_b[4], vv, 768, 768, 0);
    attn_scores<<<dim3(4, 4, 48), blk, 0, stream>>>(qc, qp, kc, kp, sc, 512, 512, SCALE);
    softmax_rows<<<dim3(48 * 512), blk, 0, stream>>>(sc, 512);
    head_mean<<<dim3(8192), blk, 0, stream>>>(sc, out_satt, 512, 512);
    attn_pv<<<dim3(4, 1, 48), blk, 0, stream>>>(sc, vv, ob, 512, 512);
    gemm_bt<bf16, false><<<dim3(6, 32), blk, 0, stream>>>(ob, nullptr, 768, sa_w[5], 768, sa_b[5], t2, 768, 768, 0);
    add_ln<float, bf16><<<dim3(4096), blk, 0, stream>>>(tgt, t2, ln_g[0], ln_b[0], t1);

    // ---- cross attention ----
    gemm_bt<float, false><<<dim3(6, 32), blk, 0, stream>>>(tgt_pos, nullptr, 768, ca_w[0], 768, ca_b[0], qc, 768, 768, 0);
    gemm_bt<bf16,  true ><<<dim3(6, 32), blk, 0, stream>>>(t1,    tgt_pos2, 768, ca_w[1], 768, ca_b[1], qp, 768, 768, 0);
    gemm_bt<float, false><<<dim3(6, 64), blk, 0, stream>>>(memory,     nullptr, 768, ca_w[2], 768, ca_b[2], kc, 768, 768, 0);
    gemm_bt<float, false><<<dim3(6, 64), blk, 0, stream>>>(memory_pos, nullptr, 768, ca_w[3], 768, ca_b[3], kp, 768, 768, 0);
    gemm_bt<float, false><<<dim3(6, 64), blk, 0, stream>>>(memory_pos, nullptr, 768, ca_w[4], 768, ca_b[4], vv, 768, 768, 0);
    attn_scores<<<dim3(8, 4, 48), blk, 0, stream>>>(qc, qp, kc, kp, sc, 512, 1024, SCALE);
    softmax_rows<<<dim3(48 * 512), blk, 0, stream>>>(sc, 1024);
    head_mean<<<dim3(16384), blk, 0, stream>>>(sc, out_att, 512, 1024);
    attn_pv<<<dim3(4, 1, 48), blk, 0, stream>>>(sc, vv, ob, 512, 1024);
    gemm_bt<bf16, false><<<dim3(6, 32), blk, 0, stream>>>(ob, nullptr, 768, ca_w[5], 768, ca_b[5], t2, 768, 768, 0);
    add_ln<bf16, bf16><<<dim3(4096), blk, 0, stream>>>(t1, t2, ln_g[1], ln_b[1], tca);

    // ---- FFN ----
    gemm_bt<bf16, false><<<dim3(16, 32), blk, 0, stream>>>(tca, nullptr, 768, ff1_w, 768, ff1_b, ffh, 2048, 768, 1);
    gemm_bt<bf16, false><<<dim3(6, 32),  blk, 0, stream>>>(ffh, nullptr, 2048, ff2_w, 2048, ff2_b, t2, 768, 2048, 0);
    add_ln<bf16, float><<<dim3(4096), blk, 0, stream>>>(tca, t2, ln_g[2], ln_b[2], out_t);
}

// Round 7
// 800.859 us; speedup vs baseline: 1.1784x; 1.1784x over previous
//
#include <hip/hip_runtime.h>

// Conditional-DETR decoder layer, MI355X gfx950. Round 7: parallelism pass.
// R6 green (943.7 us). Counters: GEMM dispatches 77 us @ 192 blocks, Occ 7.7%,
// MfmaUtil 6%, VALU 9%, HBM 11% -> latency-bound (grid < CU count).
// This round: z-fused multi-job GEMMs (SA proj x5 = 960 blocks, CA kv x3 = 1152,
// CA q x2 = 384), split-K out-projs/FFN2 with fp32 partials folded into add_ln,
// split-S attn_pv with partial pair consumed by out-proj staging.
// Dtypes: inputs fp32, outputs fp32; intermediates bf16; fp32 accum everywhere.

typedef __bf16 bf16;
typedef __attribute__((ext_vector_type(8))) __bf16 bf16x8;
typedef __attribute__((ext_vector_type(4))) float f32x4;

#define D_MODEL 768
#define NH 6
#define HD 128
#define ROWSTRIDE (8 * D_MODEL)  // 6144 (B*D)

// 8-elem staging loaders -> bf16x8
__device__ inline bf16x8 ld8f(const float* p) {
    f32x4 a = *(const f32x4*)p, b = *(const f32x4*)(p + 4);
    bf16x8 r;
#pragma unroll
    for (int i = 0; i < 4; i++) { r[i] = (bf16)a[i]; r[i + 4] = (bf16)b[i]; }
    return r;
}
__device__ inline bf16x8 ld8b(const bf16* p) { return *(const bf16x8*)p; }
__device__ inline bf16x8 ld8bf(const bf16* p, const float* q) {  // bf16 + f32
    bf16x8 x = *(const bf16x8*)p;
    f32x4 a = *(const f32x4*)q, b = *(const f32x4*)(q + 4);
    bf16x8 r;
#pragma unroll
    for (int i = 0; i < 4; i++) { r[i] = (bf16)((float)x[i] + a[i]); r[i + 4] = (bf16)((float)x[i + 4] + b[i]); }
    return r;
}
__device__ inline bf16x8 ld8ff(const float* p, const float* q) {  // f32 + f32
    f32x4 a = *(const f32x4*)p, b = *(const f32x4*)(p + 4);
    f32x4 c = *(const f32x4*)q, d = *(const f32x4*)(q + 4);
    bf16x8 r;
#pragma unroll
    for (int i = 0; i < 4; i++) { r[i] = (bf16)(a[i] + c[i]); r[i + 4] = (bf16)(b[i] + d[i]); }
    return r;
}

// ---------------------------------------------------------------------------
// Multi-job GEMM: per z-slice job: C[M,N] = A[M,K] * W[N,K]^T + bias.
// aty: 0 = A fp32, 1 = A bf16, 2 = A bf16 + A2 fp32 (summed).
// 128x128 tile, 256 thr = 4 waves (2x2), 4x4 MFMA 16x16x32 per wave.
struct Job { const void* A; const void* A2; const float* W; const float* bias;
             bf16* C; int aty; int relu; };
struct Jobs5 { Job j[5]; };

__global__ __launch_bounds__(256) void gemm_jobs(
    Jobs5 jobs, int lda, int ldw, int ldc, int K)
{
    __shared__ __align__(16) bf16 As[128][40];
    __shared__ __align__(16) bf16 Bs[128][40];
    const Job jb = jobs.j[blockIdx.z];
    const int bm = blockIdx.y * 128, bn = blockIdx.x * 128;
    const int tid = threadIdx.x;
    const int wave = tid >> 6, lane = tid & 63;
    const int wm = (wave >> 1) * 64, wn = (wave & 1) * 64;
    const int quad = lane >> 4, m16 = lane & 15;
    const int srow = tid >> 2, scol = (tid & 3) * 8;
    f32x4 acc[4][4] = {};
    const size_t aoff0 = (size_t)(bm + srow) * lda + scol;
    const size_t aoff1 = aoff0 + (size_t)64 * lda;
    const size_t woff0 = (size_t)(bn + srow) * ldw + scol;
    const size_t woff1 = woff0 + (size_t)64 * ldw;
    for (int k0 = 0; k0 < K; k0 += 32) {
        bf16x8 a0, a1;
        if (jb.aty == 0) {
            a0 = ld8f((const float*)jb.A + aoff0 + k0);
            a1 = ld8f((const float*)jb.A + aoff1 + k0);
        } else if (jb.aty == 1) {
            a0 = ld8b((const bf16*)jb.A + aoff0 + k0);
            a1 = ld8b((const bf16*)jb.A + aoff1 + k0);
        } else {
            a0 = ld8bf((const bf16*)jb.A + aoff0 + k0, (const float*)jb.A2 + aoff0 + k0);
            a1 = ld8bf((const bf16*)jb.A + aoff1 + k0, (const float*)jb.A2 + aoff1 + k0);
        }
        *(bf16x8*)&As[srow][scol]      = a0;
        *(bf16x8*)&As[srow + 64][scol] = a1;
        *(bf16x8*)&Bs[srow][scol]      = ld8f(jb.W + woff0 + k0);
        *(bf16x8*)&Bs[srow + 64][scol] = ld8f(jb.W + woff1 + k0);
        __syncthreads();
        bf16x8 af[4], bfr[4];
#pragma unroll
        for (int i = 0; i < 4; i++) {
            af[i]  = *(const bf16x8*)&As[wm + i * 16 + m16][quad * 8];
            bfr[i] = *(const bf16x8*)&Bs[wn + i * 16 + m16][quad * 8];
        }
#pragma unroll
        for (int i = 0; i < 4; i++)
#pragma unroll
            for (int j = 0; j < 4; j++)
                acc[i][j] = __builtin_amdgcn_mfma_f32_16x16x32_bf16(af[i], bfr[j], acc[i][j], 0, 0, 0);
        __syncthreads();
    }
#pragma unroll
    for (int j = 0; j < 4; j++) {
        const int col = bn + wn + j * 16 + m16;
        const float bv = jb.bias[col];
#pragma unroll
        for (int i = 0; i < 4; i++)
#pragma unroll
            for (int r = 0; r < 4; r++) {
                const int row = bm + wm + i * 16 + quad * 4 + r;
                float val = acc[i][j][r] + bv;
                if (jb.relu) val = fmaxf(val, 0.f);
                jb.C[(size_t)row * ldc + col] = (bf16)val;
            }
    }
}

// ---------------------------------------------------------------------------
// Split-K GEMM: z = K-slice; fp32 partial out (no bias — folded into add_ln).
// ATY 1 = bf16 A; ATY 3 = fp32+fp32 dual A (PV partial pair).
template <int ATY>
__global__ __launch_bounds__(256) void gemm_sk(
    const void* __restrict__ A, const void* __restrict__ A2, int lda,
    const float* __restrict__ W, int ldw,
    float* __restrict__ Cp, size_t cstride, int ldc, int Ks)
{
    __shared__ __align__(16) bf16 As[128][40];
    __shared__ __align__(16) bf16 Bs[128][40];
    const int bm = blockIdx.y * 128, bn = blockIdx.x * 128;
    const int kbase = blockIdx.z * Ks;
    const int tid = threadIdx.x;
    const int wave = tid >> 6, lane = tid & 63;
    const int wm = (wave >> 1) * 64, wn = (wave & 1) * 64;
    const int quad = lane >> 4, m16 = lane & 15;
    const int srow = tid >> 2, scol = (tid & 3) * 8;
    f32x4 acc[4][4] = {};
    const size_t aoff0 = (size_t)(bm + srow) * lda + kbase + scol;
    const size_t aoff1 = aoff0 + (size_t)64 * lda;
    const size_t woff0 = (size_t)(bn + srow) * ldw + kbase + scol;
    const size_t woff1 = woff0 + (size_t)64 * ldw;
    for (int k0 = 0; k0 < Ks; k0 += 32) {
        bf16x8 a0, a1;
        if (ATY == 1) {
            a0 = ld8b((const bf16*)A + aoff0 + k0);
            a1 = ld8b((const bf16*)A + aoff1 + k0);
        } else {
            a0 = ld8ff((const float*)A + aoff0 + k0, (const float*)A2 + aoff0 + k0);
            a1 = ld8ff((const float*)A + aoff1 + k0, (const float*)A2 + aoff1 + k0);
        }
        *(bf16x8*)&As[srow][scol]      = a0;
        *(bf16x8*)&As[srow + 64][scol] = a1;
        *(bf16x8*)&Bs[srow][scol]      = ld8f(W + woff0 + k0);
        *(bf16x8*)&Bs[srow + 64][scol] = ld8f(W + woff1 + k0);
        __syncthreads();
        bf16x8 af[4], bfr[4];
#pragma unroll
        for (int i = 0; i < 4; i++) {
            af[i]  = *(const bf16x8*)&As[wm + i * 16 + m16][quad * 8];
            bfr[i] = *(const bf16x8*)&Bs[wn + i * 16 + m16][quad * 8];
        }
#pragma unroll
        for (int i = 0; i < 4; i++)
#pragma unroll
            for (int j = 0; j < 4; j++)
                acc[i][j] = __builtin_amdgcn_mfma_f32_16x16x32_bf16(af[i], bfr[j], acc[i][j], 0, 0, 0);
        __syncthreads();
    }
    float* out = Cp + (size_t)blockIdx.z * cstride;
#pragma unroll
    for (int j = 0; j < 4; j++) {
        const int col = bn + wn + j * 16 + m16;
#pragma unroll
        for (int i = 0; i < 4; i++)
#pragma unroll
            for (int r = 0; r < 4; r++) {
                const int row = bm + wm + i * 16 + quad * 4 + r;
                out[(size_t)row * ldc + col] = acc[i][j][r];
            }
    }
}

// ---------------------------------------------------------------------------
// scores[bh,l,s] = scale*(qc.kc + qp.kp), K=256. Grid (S/128, Lq/128, B*H).
__global__ __launch_bounds__(256) void attn_scores(
    const bf16* __restrict__ qc, const bf16* __restrict__ qp,
    const bf16* __restrict__ kc, const bf16* __restrict__ kp,
    bf16* __restrict__ scores, int Lq, int S, float scale)
{
    __shared__ __align__(16) bf16 As[128][40];
    __shared__ __align__(16) bf16 Bs[128][40];
    const int bh = blockIdx.z;
    const int b = bh / NH, h = bh % NH;
    const int bm = blockIdx.y * 128, bn = blockIdx.x * 128;
    const int tid = threadIdx.x;
    const int wave = tid >> 6, lane = tid & 63;
    const int wm = (wave >> 1) * 64, wn = (wave & 1) * 64;
    const int quad = lane >> 4, m16 = lane & 15;
    const int srow = tid >> 2, scol = (tid & 3) * 8;
    f32x4 acc[4][4] = {};
    const size_t hb = (size_t)b * D_MODEL + h * HD;
    for (int k0 = 0; k0 < 256; k0 += 32) {
        const bf16* qsrc = (k0 < 128) ? qc : qp;
        const bf16* ksrc = (k0 < 128) ? kc : kp;
        const int kcol = (k0 & 127) + scol;
        *(bf16x8*)&As[srow][scol]      = *(const bf16x8*)(qsrc + (size_t)(bm + srow) * ROWSTRIDE + hb + kcol);
        *(bf16x8*)&As[srow + 64][scol] = *(const bf16x8*)(qsrc + (size_t)(bm + srow + 64) * ROWSTRIDE + hb + kcol);
        *(bf16x8*)&Bs[srow][scol]      = *(const bf16x8*)(ksrc + (size_t)(bn + srow) * ROWSTRIDE + hb + kcol);
        *(bf16x8*)&Bs[srow + 64][scol] = *(const bf16x8*)(ksrc + (size_t)(bn + srow + 64) * ROWSTRIDE + hb + kcol);
        __syncthreads();
        bf16x8 af[4], bfr[4];
#pragma unroll
        for (int i = 0; i < 4; i++) {
            af[i]  = *(const bf16x8*)&As[wm + i * 16 + m16][quad * 8];
            bfr[i] = *(const bf16x8*)&Bs[wn + i * 16 + m16][quad * 8];
        }
#pragma unroll
        for (int i = 0; i < 4; i++)
#pragma unroll
            for (int j = 0; j < 4; j++)
                acc[i][j] = __builtin_amdgcn_mfma_f32_16x16x32_bf16(af[i], bfr[j], acc[i][j], 0, 0, 0);
        __syncthreads();
    }
    bf16* sb = scores + (size_t)bh * Lq * S;
#pragma unroll
    for (int i = 0; i < 4; i++)
#pragma unroll
        for (int j = 0; j < 4; j++)
#pragma unroll
            for (int r = 0; r < 4; r++)
                sb[(size_t)(bm + wm + i * 16 + quad * 4 + r) * S + bn + wn + j * 16 + m16]
                    = (bf16)(acc[i][j][r] * scale);
}

// ---------------------------------------------------------------------------
__global__ __launch_bounds__(256) void softmax_rows(bf16* __restrict__ scores, int S)
{
    bf16* p = scores + (size_t)blockIdx.x * S;
    const int tid = threadIdx.x;
    const int n = S >> 8;
    float vals[4];
    float mx = -1e30f;
    for (int i = 0; i < n; i++) { vals[i] = (float)p[tid + (i << 8)]; mx = fmaxf(mx, vals[i]); }
    for (int off = 32; off; off >>= 1) mx = fmaxf(mx, __shfl_xor(mx, off, 64));
    __shared__ float red[4], red2[4];
    if ((tid & 63) == 0) red[tid >> 6] = mx;
    __syncthreads();
    mx = fmaxf(fmaxf(red[0], red[1]), fmaxf(red[2], red[3]));
    float sum = 0.f;
    for (int i = 0; i < n; i++) { vals[i] = __expf(vals[i] - mx); sum += vals[i]; }
    for (int off = 32; off; off >>= 1) sum += __shfl_xor(sum, off, 64);
    if ((tid & 63) == 0) red2[tid >> 6] = sum;
    __syncthreads();
    const float inv = 1.f / (red2[0] + red2[1] + red2[2] + red2[3]);
    for (int i = 0; i < n; i++) p[tid + (i << 8)] = (bf16)(vals[i] * inv);
}

__global__ __launch_bounds__(256) void head_mean(
    const bf16* __restrict__ w, float* __restrict__ att, int Lq, int S)
{
    const size_t idx = (size_t)blockIdx.x * 256 + threadIdx.x;
    const size_t s = idx % S, rem = idx / S;
    const size_t l = rem % Lq, b = rem / Lq;
    float sum = 0.f;
#pragma unroll
    for (int h = 0; h < NH; h++)
        sum += (float)w[((b * NH + h) * Lq + l) * (size_t)S + s];
    att[idx] = sum * (1.f / 6.f);
}

// ---------------------------------------------------------------------------
// Split-S PV: Pv[y][l, b*768+h*128+e] = sum over S-half y. Grid (Lq/128, 2, B*H).
__global__ __launch_bounds__(256) void attn_pv_sk(
    const bf16* __restrict__ wsm, const bf16* __restrict__ v,
    float* __restrict__ Pv, size_t pstride, int Lq, int S)
{
    __shared__ __align__(16) bf16 As[128][40];
    __shared__ __align__(16) bf16 BsT[128][40];
    const int bh = blockIdx.z;
    const int b = bh / NH, h = bh % NH;
    const int bm = blockIdx.x * 128;
    const int kbase = blockIdx.y * (S >> 1);
    const int tid = threadIdx.x;
    const int wave = tid >> 6, lane = tid & 63;
    const int wm = (wave >> 1) * 64, wn = (wave & 1) * 64;
    const int quad = lane >> 4, m16 = lane & 15;
    const int srow = tid >> 2, scol = (tid & 3) * 8;
    const int kk0 = tid >> 4, e0 = (tid & 15) * 8;
    f32x4 acc[4][4] = {};
    const bf16* wbase = wsm + (size_t)(bh * Lq + bm) * S + kbase;
    const size_t vb = (size_t)b * D_MODEL + h * HD;
    for (int k0 = 0; k0 < (S >> 1); k0 += 32) {
        *(bf16x8*)&As[srow][scol]      = *(const bf16x8*)(wbase + (size_t)srow * S + k0 + scol);
        *(bf16x8*)&As[srow + 64][scol] = *(const bf16x8*)(wbase + (size_t)(srow + 64) * S + k0 + scol);
        bf16x8 v0 = *(const bf16x8*)(v + (size_t)(kbase + k0 + kk0) * ROWSTRIDE + vb + e0);
        bf16x8 v1 = *(const bf16x8*)(v + (size_t)(kbase + k0 + kk0 + 16) * ROWSTRIDE + vb + e0);
#pragma unroll
        for (int i = 0; i < 8; i++) { BsT[e0 + i][kk0] = v0[i]; BsT[e0 + i][kk0 + 16] = v1[i]; }
        __syncthreads();
        bf16x8 af[4], bfr[4];
#pragma unroll
        for (int i = 0; i < 4; i++) {
            af[i]  = *(const bf16x8*)&As[wm + i * 16 + m16][quad * 8];
            bfr[i] = *(const bf16x8*)&BsT[wn + i * 16 + m16][quad * 8];
        }
#pragma unroll
        for (int i = 0; i < 4; i++)
#pragma unroll
            for (int j = 0; j < 4; j++)
                acc[i][j] = __builtin_amdgcn_mfma_f32_16x16x32_bf16(af[i], bfr[j], acc[i][j], 0, 0, 0);
        __syncthreads();
    }
    float* out = Pv + blockIdx.y * pstride;
#pragma unroll
    for (int i = 0; i < 4; i++)
#pragma unroll
        for (int j = 0; j < 4; j++)
#pragma unroll
            for (int r = 0; r < 4; r++)
                out[(size_t)(bm + wm + i * 16 + quad * 4 + r) * ROWSTRIDE + vb + wn + j * 16 + m16]
                    = acc[i][j][r];
}

// ---------------------------------------------------------------------------
// out = LN(resid + sum_{p<NP} P[p] + xbias) * g + be.
template <int NP, typename TR, typename TO>
__global__ __launch_bounds__(256) void add_ln_p(
    const TR* __restrict__ resid, const float* __restrict__ P, size_t pstride,
    const float* __restrict__ xbias,
    const float* __restrict__ g, const float* __restrict__ be, TO* __restrict__ out)
{
    const size_t base = (size_t)blockIdx.x * D_MODEL;
    const int tid = threadIdx.x;
    float v[3];
#pragma unroll
    for (int i = 0; i < 3; i++) {
        const int c = tid + (i << 8);
        float x = xbias[c];
#pragma unroll
        for (int p = 0; p < NP; p++) x += P[p * pstride + base + c];
        v[i] = (float)resid[base + c] + x;
    }
    float s = v[0] + v[1] + v[2];
    float s2 = v[0] * v[0] + v[1] * v[1] + v[2] * v[2];
    for (int off = 32; off; off >>= 1) { s += __shfl_xor(s, off, 64); s2 += __shfl_xor(s2, off, 64); }
    __shared__ float rs[4], rs2[4];
    if ((tid & 63) == 0) { rs[tid >> 6] = s; rs2[tid >> 6] = s2; }
    __syncthreads();
    s = rs[0] + rs[1] + rs[2] + rs[3];
    s2 = rs2[0] + rs2[1] + rs2[2] + rs2[3];
    const float mean = s * (1.f / 768.f);
    const float var = s2 * (1.f / 768.f) - mean * mean;
    const float inv = rsqrtf(var + 1e-5f);
#pragma unroll
    for (int i = 0; i < 3; i++) {
        const int c = tid + (i << 8);
        out[base + c] = (TO)((v[i] - mean) * inv * g[c] + be[c]);
    }
}

// ---------------------------------------------------------------------------
extern "C" void kernel_launch(void* const* d_in, const int* in_sizes, int n_in,
                              void* d_out, int out_size, void* d_ws, size_t ws_size,
                              hipStream_t stream)
{
    const float* tgt        = (const float*)d_in[0];
    const float* memory     = (const float*)d_in[1];
    const float* tgt_pos    = (const float*)d_in[2];
    const float* memory_pos = (const float*)d_in[3];
    const float* tgt_pos2   = (const float*)d_in[4];
    const float *sa_w[6], *sa_b[6], *ca_w[6], *ca_b[6];
    for (int i = 0; i < 6; i++) {
        sa_w[i] = (const float*)d_in[5 + 2 * i];  sa_b[i] = (const float*)d_in[6 + 2 * i];
        ca_w[i] = (const float*)d_in[17 + 2 * i]; ca_b[i] = (const float*)d_in[18 + 2 * i];
    }
    const float* ff1_w = (const float*)d_in[29]; const float* ff1_b = (const float*)d_in[30];
    const float* ff2_w = (const float*)d_in[31]; const float* ff2_b = (const float*)d_in[32];
    const float* ln_g[3] = {(const float*)d_in[33], (const float*)d_in[35], (const float*)d_in[37]};
    const float* ln_b[3] = {(const float*)d_in[34], (const float*)d_in[36], (const float*)d_in[38]};

    // ---- workspace (106,954,752 B) ----
    char* ws = (char*)d_ws;
    bf16* qc  = (bf16*)(ws);                // [0, 6291456)
    bf16* qp  = (bf16*)(ws + 6291456);      // [6291456, 12582912)
    bf16* kc  = (bf16*)(ws + 12582912);     // [12582912, 25165824)
    bf16* kp  = (bf16*)(ws + 25165824);     // [25165824, 37748736)
    bf16* vv  = (bf16*)(ws + 37748736);     // [37748736, 50331648)
    bf16* t1  = (bf16*)(ws + 50331648);     // [50331648, 56623104)
    bf16* sc  = (bf16*)(ws + 56623104);     // [56623104, 106954752) 50.33 MB
    // fp32 partial regions (all liveness-checked vs the launch sequence):
    const size_t PSTRIDE = 3145728;  // floats per 12.58 MB slice
    float* pv_sa = (float*)(ws + 81788928);  // sc_hi: SA PV pair (sc_lo = SA scores live)
    float* pv_ca = (float*)(ws + 12582912);  // kc+kp: dead after CA scores
    float* op    = (float*)(ws + 56623104);  // sc_lo: out-proj pair (both phases)
    float* fp    = (float*)(ws + 56623104);  // FFN2 4-slice = full sc (dead)
    bf16*  tca   = kc;                       // Pv_ca dead after CA out-proj
    bf16*  ffh   = kp;                       // 16.78 MB over dead kp+vv

    float* out_t    = (float*)d_out;        // (L,B,D)
    float* out_att  = out_t + 3145728;      // (B,L,S)
    float* out_satt = out_att + 4194304;    // (B,L,L)

    const dim3 blk(256);
    const float SCALE = 0.0625f;

    // ---- self attention ----
    {
        Jobs5 J;
        J.j[0] = {tgt_pos, nullptr, sa_w[0], sa_b[0], qc, 0, 0};
        J.j[1] = {tgt,     nullptr, sa_w[1], sa_b[1], qp, 0, 0};
        J.j[2] = {tgt_pos, nullptr, sa_w[2], sa_b[2], kc, 0, 0};
        J.j[3] = {tgt,     nullptr, sa_w[3], sa_b[3], kp, 0, 0};
        J.j[4] = {tgt,     nullptr, sa_w[4], sa_b[4], vv, 0, 0};
        gemm_jobs<<<dim3(6, 32, 5), blk, 0, stream>>>(J, 768, 768, 768, 768);
    }
    attn_scores<<<dim3(4, 4, 48), blk, 0, stream>>>(qc, qp, kc, kp, sc, 512, 512, SCALE);
    softmax_rows<<<dim3(48 * 512), blk, 0, stream>>>(sc, 512);
    head_mean<<<dim3(8192), blk, 0, stream>>>(sc, out_satt, 512, 512);
    attn_pv_sk<<<dim3(4, 2, 48), blk, 0, stream>>>(sc, vv, pv_sa, PSTRIDE, 512, 512);
    gemm_sk<3><<<dim3(6, 32, 2), blk, 0, stream>>>(pv_sa, pv_sa + PSTRIDE, 768,
                                                   sa_w[5], 768, op, PSTRIDE, 768, 384);
    add_ln_p<2, float, bf16><<<dim3(4096), blk, 0, stream>>>(tgt, op, PSTRIDE, sa_b[5],
                                                             ln_g[0], ln_b[0], t1);

    // ---- cross attention ----
    {
        Jobs5 J = {};
        J.j[0] = {tgt_pos, nullptr,  ca_w[0], ca_b[0], qc, 0, 0};
        J.j[1] = {t1,      tgt_pos2, ca_w[1], ca_b[1], qp, 2, 0};
        gemm_jobs<<<dim3(6, 32, 2), blk, 0, stream>>>(J, 768, 768, 768, 768);
    }
    {
        Jobs5 J = {};
        J.j[0] = {memory,     nullptr, ca_w[2], ca_b[2], kc, 0, 0};
        J.j[1] = {memory_pos, nullptr, ca_w[3], ca_b[3], kp, 0, 0};
        J.j[2] = {memory_pos, nullptr, ca_w[4], ca_b[4], vv, 0, 0};
        gemm_jobs<<<dim3(6, 64, 3), blk, 0, stream>>>(J, 768, 768, 768, 768);
    }
    attn_scores<<<dim3(8, 4, 48), blk, 0, stream>>>(qc, qp, kc, kp, sc, 512, 1024, SCALE);
    softmax_rows<<<dim3(48 * 512), blk, 0, stream>>>(sc, 1024);
    head_mean<<<dim3(16384), blk, 0, stream>>>(sc, out_att, 512, 1024);
    attn_pv_sk<<<dim3(4, 2, 48), blk, 0, stream>>>(sc, vv, pv_ca, PSTRIDE, 512, 1024);
    gemm_sk<3><<<dim3(6, 32, 2), blk, 0, stream>>>(pv_ca, pv_ca + PSTRIDE, 768,
                                                   ca_w[5], 768, op, PSTRIDE, 768, 384);
    add_ln_p<2, bf16, bf16><<<dim3(4096), blk, 0, stream>>>(t1, op, PSTRIDE, ca_b[5],
                                                            ln_g[1], ln_b[1], tca);

    // ---- FFN ----
    {
        Jobs5 J = {};
        J.j[0] = {tca, nullptr, ff1_w, ff1_b, ffh, 1, 1};
        gemm_jobs<<<dim3(16, 32, 1), blk, 0, stream>>>(J, 768, 768, 2048, 768);
    }
    gemm_sk<1><<<dim3(6, 32, 4), blk, 0, stream>>>(ffh, nullptr, 2048,
                                                   ff2_w, 2048, fp, PSTRIDE, 768, 512);
    add_ln_p<4, bf16, float><<<dim3(4096), blk, 0, stream>>>(tca, fp, PSTRIDE, ff2_b,
                                                             ln_g[2], ln_b[2], out_t);
}